// Round 3
// baseline (432.748 us; speedup 1.0000x reference)
//
#include <hip/hip_runtime.h>
#include <hip/hip_bf16.h>

// LearnableVQ forward on MI355X.
// B=8 H=8 L=4096 DK=64 S=512. Inputs f32; output FLOAT32, concatenated:
//   vecs_hat[B,H,L,DK] | z[B,H,L] | l_commit | l_codebook | errs2[B,H,L]
// Numerically: vecs_hat = c[h, z]; l_codebook = 0 (straight-through terms vanish).

#define Bc 8
#define Hc 8
#define Lc 4096
#define DKc 64
#define Sc 512

// ---------------- ws layout (bytes) ----------------
#define WS_C_OFF    0u          // H*S*DK f32 = 1,048,576 B
#define WS_C2_OFF   1048576u    // H*S f32   = 16,384 B
#define WS_PART_OFF 1064960u    // 2048 doubles = 16,384 B
#define NPART       2048

// ---------------- prep: c = c_sum / max(c_count, 0.01); c2 = sum c^2 ----------------
__global__ __launch_bounds__(256) void prep_kernel(
        const float* __restrict__ c_sum,
        const float* __restrict__ c_count,
        float* __restrict__ c,
        float* __restrict__ c2) {
    int wave = (blockIdx.x * blockDim.x + threadIdx.x) >> 6;   // (h,s) index
    int lane = threadIdx.x & 63;
    if (wave >= Hc * Sc) return;
    float cnt = c_count[wave];
    float inv = 1.0f / fmaxf(cnt, 0.01f);
    float val = c_sum[wave * DKc + lane] * inv;
    c[wave * DKc + lane] = val;
    float sq = val * val;
    #pragma unroll
    for (int off = 32; off; off >>= 1) sq += __shfl_xor(sq, off);
    if (lane == 0) c2[wave] = sq;
}

// ---------------- fused: distance GEMM -> per-row top-2 -> f64 refine -> outputs ----------------
#define TR 128      // rows per block
#define TCC 64      // codes per chunk
#define APAD 4      // LDS stride pad

__global__ __launch_bounds__(256) void vq_fused_kernel(
        const float* __restrict__ vecs,
        const float* __restrict__ c,
        const float* __restrict__ c2,
        const float* __restrict__ loss_mask,
        float* __restrict__ out_vh,
        float* __restrict__ out_z,
        float* __restrict__ out_err,
        double* __restrict__ partials) {
    __shared__ float  a_lds[DKc][TR + APAD];    // 33,792 B  (k-major rows)
    __shared__ float  b_lds[DKc][TCC + APAD];   // 17,408 B  (k-major codes)
    __shared__ float  c2_lds[Sc];               //  2,048 B
    __shared__ int2   top2[TR];                 //  1,024 B
    __shared__ double wsum8[8];                 //     64 B   -> total 54,336 B

    const int t  = threadIdx.x;
    const int bh = blockIdx.y;          // b*H + h
    const int h  = bh & (Hc - 1);
    const int b  = bh >> 3;
    const int lt = blockIdx.x;          // l-tile

    const float* A  = vecs + ((size_t)bh * Lc + (size_t)lt * TR) * DKc;
    const float* Bp = c + (size_t)h * Sc * DKc;

    for (int i = t; i < Sc; i += 256) c2_lds[i] = c2[h * Sc + i];

    // stage A transposed: a_lds[k][row]
    #pragma unroll
    for (int i = 0; i < 8; ++i) {
        int e = i * 256 + t;            // float4 index: 128 rows x 16 quads
        int r = e >> 4;
        int q = e & 15;
        float4 v = reinterpret_cast<const float4*>(A)[e];
        a_lds[q * 4 + 0][r] = v.x;
        a_lds[q * 4 + 1][r] = v.y;
        a_lds[q * 4 + 2][r] = v.z;
        a_lds[q * 4 + 3][r] = v.w;
    }

    const int tr = t >> 4;              // row group 0..15
    const int tc = t & 15;              // code group 0..15
    const int r0 = tr * 8;
    const int c0 = tc * 4;

    float v1[8], v2v[8];
    int   i1[8], i2[8];
    #pragma unroll
    for (int i = 0; i < 8; ++i) { v1[i] = 3.0e38f; v2v[i] = 3.0e38f; i1[i] = 0; i2[i] = 0; }

    for (int chunk = 0; chunk < Sc / TCC; ++chunk) {
        __syncthreads();
        // stage B chunk transposed: b_lds[k][code]
        #pragma unroll
        for (int i = 0; i < 4; ++i) {
            int e = i * 256 + t;        // float4 index: 64 codes x 16 quads
            int s = e >> 4;
            int q = e & 15;
            float4 v = reinterpret_cast<const float4*>(Bp + (size_t)chunk * TCC * DKc)[e];
            b_lds[q * 4 + 0][s] = v.x;
            b_lds[q * 4 + 1][s] = v.y;
            b_lds[q * 4 + 2][s] = v.z;
            b_lds[q * 4 + 3][s] = v.w;
        }
        __syncthreads();

        float acc[8][4];
        #pragma unroll
        for (int i = 0; i < 8; ++i)
            #pragma unroll
            for (int j = 0; j < 4; ++j) acc[i][j] = 0.0f;

        #pragma unroll 4
        for (int k = 0; k < DKc; ++k) {
            float4 a0 = *reinterpret_cast<const float4*>(&a_lds[k][r0]);
            float4 a1 = *reinterpret_cast<const float4*>(&a_lds[k][r0 + 4]);
            float4 b0 = *reinterpret_cast<const float4*>(&b_lds[k][c0]);
            float av[8] = {a0.x, a0.y, a0.z, a0.w, a1.x, a1.y, a1.z, a1.w};
            float bv[4] = {b0.x, b0.y, b0.z, b0.w};
            #pragma unroll
            for (int i = 0; i < 8; ++i)
                #pragma unroll
                for (int j = 0; j < 4; ++j)
                    acc[i][j] = fmaf(av[i], bv[j], acc[i][j]);
        }

        // fold into running top-2 (ascending codes within thread -> '<' keeps earliest)
        #pragma unroll
        for (int j = 0; j < 4; ++j) {
            int code = chunk * TCC + c0 + j;
            float cc = c2_lds[code];
            #pragma unroll
            for (int i = 0; i < 8; ++i) {
                float d = fmaf(-2.0f, acc[i][j], cc);
                if (d < v1[i]) { v2v[i] = v1[i]; i2[i] = i1[i]; v1[i] = d; i1[i] = code; }
                else if (d < v2v[i]) { v2v[i] = d; i2[i] = code; }
            }
        }
    }

    // cross-thread top-2 reduce over the 16 code-groups sharing each row
    __syncthreads();
    float* scr = &a_lds[0][0];          // reuse: 128*16 float4 = 32 KiB <= a_lds
    #pragma unroll
    for (int i = 0; i < 8; ++i) {
        float4 pk = make_float4(v1[i], __int_as_float(i1[i]), v2v[i], __int_as_float(i2[i]));
        reinterpret_cast<float4*>(scr)[(r0 + i) * 16 + tc] = pk;
    }
    __syncthreads();
    if (t < TR) {
        float bv1 = 3.0e38f, bv2 = 3.0e38f; int bi1 = 0, bi2 = 0;
        #pragma unroll
        for (int g = 0; g < 16; ++g) {
            float4 pk = reinterpret_cast<const float4*>(scr)[t * 16 + g];
            float w1 = pk.x; int j1 = __float_as_int(pk.y);
            float w2 = pk.z; int j2 = __float_as_int(pk.w);
            bool firstWins = (w1 < bv1) || (w1 == bv1 && j1 < bi1);
            if (firstWins) {
                float nv2; int ni2;
                if (bv1 < w2 || (bv1 == w2 && bi1 < j2)) { nv2 = bv1; ni2 = bi1; }
                else                                     { nv2 = w2;  ni2 = j2; }
                bv1 = w1; bi1 = j1; bv2 = nv2; bi2 = ni2;
            } else {
                if (w1 < bv2 || (w1 == bv2 && j1 < bi2)) { bv2 = w1; bi2 = j1; }
            }
        }
        top2[t] = make_int2(bi1, bi2);
    }
    __syncthreads();

    // ---- in-block f64 refine: half-wave (32 lanes) per row, 16 iters x 8 half-waves ----
    const int half = t >> 5;            // 0..7
    const int hl   = t & 31;            // lane within half-wave
    double acc_c = 0.0;
    for (int it = 0; it < 16; ++it) {
        int  row  = it * 8 + half;      // 0..127
        int  l    = lt * TR + row;
        long grow = (long)bh * Lc + l;
        int2 zz   = top2[row];
        float vlo  = A[row * DKc + hl];
        float vhi  = A[row * DKc + hl + 32];
        const float* C1 = Bp + (size_t)zz.x * DKc;
        const float* C2 = Bp + (size_t)zz.y * DKc;
        float c1lo = C1[hl], c1hi = C1[hl + 32];
        float c2lo = C2[hl], c2hi = C2[hl + 32];
        double s_vv  = (double)vlo * vlo  + (double)vhi * vhi;
        double s_vc1 = (double)vlo * c1lo + (double)vhi * c1hi;
        double s_vc2 = (double)vlo * c2lo + (double)vhi * c2hi;
        double s_c1  = (double)c1lo * c1lo + (double)c1hi * c1hi;
        double s_c2  = (double)c2lo * c2lo + (double)c2hi * c2hi;
        #pragma unroll
        for (int off = 16; off; off >>= 1) {
            s_vv  += __shfl_xor(s_vv,  off);
            s_vc1 += __shfl_xor(s_vc1, off);
            s_vc2 += __shfl_xor(s_vc2, off);
            s_c1  += __shfl_xor(s_c1,  off);
            s_c2  += __shfl_xor(s_c2,  off);
        }
        double d1 = s_vv - 2.0 * s_vc1 + s_c1;
        double d2 = s_vv - 2.0 * s_vc2 + s_c2;
        bool second = (d2 < d1) || (d2 == d1 && zz.y < zz.x);
        int    zsel = second ? zz.y : zz.x;
        double dsel = second ? d2 : d1;
        float  cslo = second ? c2lo : c1lo;
        float  cshi = second ? c2hi : c1hi;
        double err  = dsel > 0.0 ? dsel : 0.0;
        out_vh[grow * DKc + hl]      = cslo;
        out_vh[grow * DKc + hl + 32] = cshi;
        if (hl == 0) {
            out_z[grow]   = (float)zsel;
            out_err[grow] = (float)err;
            acc_c += (double)loss_mask[b * Lc + l] * err;
        }
    }
    if (hl == 0) wsum8[half] = acc_c;
    __syncthreads();
    if (t == 0) {
        double s = 0.0;
        #pragma unroll
        for (int i = 0; i < 8; ++i) s += wsum8[i];
        partials[blockIdx.y * gridDim.x + blockIdx.x] = s;
    }
}

// ---------------- finalize: deterministic sum of partials -> l_commit, l_codebook ----------------
__global__ __launch_bounds__(256) void finalize_kernel(
        const double* __restrict__ partials, int n,
        float* __restrict__ out_lcommit, float* __restrict__ out_lcode) {
    __shared__ double sh[256];
    double a = 0.0;
    for (int i = threadIdx.x; i < n; i += 256) a += partials[i];
    sh[threadIdx.x] = a;
    __syncthreads();
    for (int s = 128; s; s >>= 1) {
        if (threadIdx.x < s) sh[threadIdx.x] += sh[threadIdx.x + s];
        __syncthreads();
    }
    if (threadIdx.x == 0) {
        double lc = sh[0] / (double)(Bc * Lc);
        *out_lcommit = (float)lc;
        *out_lcode   = 0.0f;
    }
}

extern "C" void kernel_launch(void* const* d_in, const int* in_sizes, int n_in,
                              void* d_out, int out_size, void* d_ws, size_t ws_size,
                              hipStream_t stream) {
    const float* vecs      = (const float*)d_in[0];
    const float* c_sum     = (const float*)d_in[1];
    const float* c_count   = (const float*)d_in[2];
    const float* loss_mask = (const float*)d_in[3];
    (void)in_sizes; (void)n_in; (void)out_size; (void)ws_size;

    char* ws = (char*)d_ws;
    float*  c        = (float*)(ws + WS_C_OFF);
    float*  c2       = (float*)(ws + WS_C2_OFF);
    double* partials = (double*)(ws + WS_PART_OFF);

    float* out = (float*)d_out;
    float* out_vh      = out;                                   // B*H*L*DK
    float* out_z       = out + (size_t)Bc * Hc * Lc * DKc;      // B*H*L
    float* out_lcommit = out_z + (size_t)Bc * Hc * Lc;          // 1
    float* out_lcode   = out_lcommit + 1;                       // 1
    float* out_err     = out_lcode + 1;                         // B*H*L

    // 1) codebook normalize + norms
    prep_kernel<<<(Hc * Sc * 64) / 256, 256, 0, stream>>>(c_sum, c_count, c, c2);

    // 2) fused distance GEMM + top-2 + f64 refine + outputs + partials
    dim3 g2(Lc / TR, Bc * Hc);          // (32, 64) -> 2048 blocks
    vq_fused_kernel<<<g2, 256, 0, stream>>>(vecs, c, c2, loss_mask,
                                            out_vh, out_z, out_err, partials);

    // 3) deterministic scalar reduction
    finalize_kernel<<<1, 256, 0, stream>>>(partials, NPART, out_lcommit, out_lcode);
}

// Round 4
// 335.633 us; speedup vs baseline: 1.2893x; 1.2893x over previous
//
#include <hip/hip_runtime.h>
#include <hip/hip_bf16.h>

// LearnableVQ forward on MI355X — MFMA (bf16 3-term split) distance GEMM.
// B=8 H=8 L=4096 DK=64 S=512. Inputs f32; output f32, concatenated:
//   vecs_hat[B,H,L,DK] | z[B,H,L] | l_commit | l_codebook | errs2[B,H,L]

#define Bc 8
#define Hc 8
#define Lc 4096
#define DKc 64
#define Sc 512

typedef __attribute__((ext_vector_type(8))) short bf16x8;
typedef __attribute__((ext_vector_type(4))) float f32x4;

// ---------------- ws layout (bytes) ----------------
#define WS_C_OFF    0u          // H*S*DK f32 = 1,048,576 B
#define WS_C2_OFF   1048576u    // H*S f32   = 16,384 B
#define WS_PART_OFF 1064960u    // 2048 doubles = 16,384 B
#define NPART       2048

__device__ __forceinline__ unsigned short f32_to_bf16_rne(float x) {
    unsigned u = __float_as_uint(x);
    unsigned r = (u + 0x7FFFu + ((u >> 16) & 1u)) >> 16;
    return (unsigned short)r;
}
__device__ __forceinline__ float bf16_hi_f32(unsigned short h) {
    return __uint_as_float(((unsigned)h) << 16);
}

// ---------------- prep: c = c_sum / max(c_count, 0.01); c2 = sum c^2 ----------------
__global__ __launch_bounds__(256) void prep_kernel(
        const float* __restrict__ c_sum,
        const float* __restrict__ c_count,
        float* __restrict__ c,
        float* __restrict__ c2) {
    int wave = (blockIdx.x * blockDim.x + threadIdx.x) >> 6;   // (h,s)
    int lane = threadIdx.x & 63;
    if (wave >= Hc * Sc) return;
    float cnt = c_count[wave];
    float inv = 1.0f / fmaxf(cnt, 0.01f);
    float val = c_sum[wave * DKc + lane] * inv;
    c[wave * DKc + lane] = val;
    float sq = val * val;
    #pragma unroll
    for (int off = 32; off; off >>= 1) sq += __shfl_xor(sq, off);
    if (lane == 0) c2[wave] = sq;
}

// ---------------- fused MFMA kernel ----------------
// Block: 256 thr (4 waves), 128 rows. Wave owns 32 rows (2 row-tiles of 16).
// Codes chunked 128 (4 chunks of 8 16-wide tiles). bf16 split hi/lo, 3-term MFMA.
#define TRB 128

__global__ __launch_bounds__(256) void vq_mfma_kernel(
        const float* __restrict__ vecs,
        const float* __restrict__ c,
        const float* __restrict__ c2,
        const float* __restrict__ loss_mask,
        float* __restrict__ out_vh,
        float* __restrict__ out_z,
        float* __restrict__ out_err,
        double* __restrict__ partials) {
    __shared__ unsigned short ahi[TRB * DKc];   // 16 KiB, row stride 128 B, XOR-swizzled
    __shared__ unsigned short alo[TRB * DKc];   // 16 KiB
    __shared__ unsigned short bhi[128 * DKc];   // 16 KiB
    __shared__ unsigned short blo[128 * DKc];   // 16 KiB
    __shared__ float  c2_lds[Sc];               //  2 KiB
    __shared__ int2   top2s[TRB];               //  1 KiB
    __shared__ double wsum8[8];                 // total ~67.1 KiB -> 2 blocks/CU

    const int t  = threadIdx.x;
    const int l  = t & 63;
    const int w  = t >> 6;
    const int bh = blockIdx.y;          // b*H + h
    const int h  = bh & (Hc - 1);
    const int b  = bh >> 3;
    const int lt = blockIdx.x;          // l-tile (128 rows)

    const float* Avec = vecs + ((size_t)bh * Lc + (size_t)lt * TRB) * DKc;
    const float* Bp   = c + (size_t)h * Sc * DKc;

    for (int i = t; i < Sc; i += 256) c2_lds[i] = c2[h * Sc + i];

    // ---- stage A: 128x64 f32 -> bf16 hi/lo, swizzled ----
    const float4* A4 = reinterpret_cast<const float4*>(Avec);
    #pragma unroll
    for (int i = 0; i < 8; ++i) {
        int e = i * 256 + t;            // 2048 float4
        int r = e >> 4, q = e & 15;
        float4 v = A4[e];
        ushort4 hv, lv;
        hv.x = f32_to_bf16_rne(v.x); lv.x = f32_to_bf16_rne(v.x - bf16_hi_f32(hv.x));
        hv.y = f32_to_bf16_rne(v.y); lv.y = f32_to_bf16_rne(v.y - bf16_hi_f32(hv.y));
        hv.z = f32_to_bf16_rne(v.z); lv.z = f32_to_bf16_rne(v.z - bf16_hi_f32(hv.z));
        hv.w = f32_to_bf16_rne(v.w); lv.w = f32_to_bf16_rne(v.w - bf16_hi_f32(hv.w));
        int off = (r * 128 + q * 8) ^ ((r & 7) << 4);
        *reinterpret_cast<ushort4*>((char*)ahi + off) = hv;
        *reinterpret_cast<ushort4*>((char*)alo + off) = lv;
    }
    // ---- stage B chunk 0 ----
    {
        const float4* B4 = reinterpret_cast<const float4*>(Bp);
        #pragma unroll
        for (int i = 0; i < 8; ++i) {
            int e = i * 256 + t;        // 2048 float4 (128 codes x 16 quads)
            int s = e >> 4, q = e & 15;
            float4 v = B4[e];
            ushort4 hv, lv;
            hv.x = f32_to_bf16_rne(v.x); lv.x = f32_to_bf16_rne(v.x - bf16_hi_f32(hv.x));
            hv.y = f32_to_bf16_rne(v.y); lv.y = f32_to_bf16_rne(v.y - bf16_hi_f32(hv.y));
            hv.z = f32_to_bf16_rne(v.z); lv.z = f32_to_bf16_rne(v.z - bf16_hi_f32(hv.z));
            hv.w = f32_to_bf16_rne(v.w); lv.w = f32_to_bf16_rne(v.w - bf16_hi_f32(hv.w));
            int off = (s * 128 + q * 8) ^ ((s & 7) << 4);
            *reinterpret_cast<ushort4*>((char*)bhi + off) = hv;
            *reinterpret_cast<ushort4*>((char*)blo + off) = lv;
        }
    }
    __syncthreads();

    // ---- A fragments (persist across chunks): [rt][ks] ----
    bf16x8 fah[2][2], fal[2][2];
    #pragma unroll
    for (int rt = 0; rt < 2; ++rt)
        #pragma unroll
        for (int ks = 0; ks < 2; ++ks) {
            int row = (w << 5) + (rt << 4) + (l & 15);
            int off = (row * 128 + (ks << 6) + ((l >> 4) << 4)) ^ ((row & 7) << 4);
            fah[rt][ks] = *reinterpret_cast<const bf16x8*>((const char*)ahi + off);
            fal[rt][ks] = *reinterpret_cast<const bf16x8*>((const char*)alo + off);
        }

    // per-lane top-2 state: rows (w*32 + rt*16 + (l>>4)*4 + r)
    float v1[2][4], v2[2][4];
    int   i1[2][4], i2[2][4];
    #pragma unroll
    for (int rt = 0; rt < 2; ++rt)
        #pragma unroll
        for (int r = 0; r < 4; ++r) { v1[rt][r] = 3.0e38f; v2[rt][r] = 3.0e38f; i1[rt][r] = 0; i2[rt][r] = 0; }

    float4 pre[8];
    for (int chunk = 0; chunk < 4; ++chunk) {
        // prefetch next chunk's codebook into regs (latency hides under MFMA)
        if (chunk < 3) {
            const float4* Bn = reinterpret_cast<const float4*>(Bp + (size_t)(chunk + 1) * 128 * DKc);
            #pragma unroll
            for (int i = 0; i < 8; ++i) pre[i] = Bn[i * 256 + t];
        }

        f32x4 acc[2][8];
        #pragma unroll
        for (int rt = 0; rt < 2; ++rt)
            #pragma unroll
            for (int j = 0; j < 8; ++j) acc[rt][j] = (f32x4){0.f, 0.f, 0.f, 0.f};

        #pragma unroll
        for (int j = 0; j < 8; ++j) {
            int crow = (j << 4) + (l & 15);
            int o0 = (crow * 128 + ((l >> 4) << 4)) ^ ((crow & 7) << 4);
            int o1 = (crow * 128 + 64 + ((l >> 4) << 4)) ^ ((crow & 7) << 4);
            bf16x8 h0 = *reinterpret_cast<const bf16x8*>((const char*)bhi + o0);
            bf16x8 h1 = *reinterpret_cast<const bf16x8*>((const char*)bhi + o1);
            bf16x8 g0 = *reinterpret_cast<const bf16x8*>((const char*)blo + o0);
            bf16x8 g1 = *reinterpret_cast<const bf16x8*>((const char*)blo + o1);
            #pragma unroll
            for (int rt = 0; rt < 2; ++rt) {
                acc[rt][j] = __builtin_amdgcn_mfma_f32_16x16x32_bf16(fah[rt][0], h0, acc[rt][j], 0, 0, 0);
                acc[rt][j] = __builtin_amdgcn_mfma_f32_16x16x32_bf16(fah[rt][1], h1, acc[rt][j], 0, 0, 0);
                acc[rt][j] = __builtin_amdgcn_mfma_f32_16x16x32_bf16(fal[rt][0], h0, acc[rt][j], 0, 0, 0);
                acc[rt][j] = __builtin_amdgcn_mfma_f32_16x16x32_bf16(fal[rt][1], h1, acc[rt][j], 0, 0, 0);
                acc[rt][j] = __builtin_amdgcn_mfma_f32_16x16x32_bf16(fah[rt][0], g0, acc[rt][j], 0, 0, 0);
                acc[rt][j] = __builtin_amdgcn_mfma_f32_16x16x32_bf16(fah[rt][1], g1, acc[rt][j], 0, 0, 0);
            }
        }

        // fold distances into per-lane top-2 (codes ascend -> earliest-index ties)
        #pragma unroll
        for (int j = 0; j < 8; ++j) {
            int code = (chunk << 7) + (j << 4) + (l & 15);
            float cc = c2_lds[code];
            #pragma unroll
            for (int rt = 0; rt < 2; ++rt)
                #pragma unroll
                for (int r = 0; r < 4; ++r) {
                    float d = fmaf(-2.0f, acc[rt][j][r], cc);
                    if (d < v1[rt][r]) { v2[rt][r] = v1[rt][r]; i2[rt][r] = i1[rt][r]; v1[rt][r] = d; i1[rt][r] = code; }
                    else if (d < v2[rt][r]) { v2[rt][r] = d; i2[rt][r] = code; }
                }
        }

        __syncthreads();    // all waves done reading bhi/blo
        if (chunk < 3) {
            #pragma unroll
            for (int i = 0; i < 8; ++i) {
                int e = i * 256 + t;
                int s = e >> 4, q = e & 15;
                float4 v = pre[i];
                ushort4 hv, lv;
                hv.x = f32_to_bf16_rne(v.x); lv.x = f32_to_bf16_rne(v.x - bf16_hi_f32(hv.x));
                hv.y = f32_to_bf16_rne(v.y); lv.y = f32_to_bf16_rne(v.y - bf16_hi_f32(hv.y));
                hv.z = f32_to_bf16_rne(v.z); lv.z = f32_to_bf16_rne(v.z - bf16_hi_f32(hv.z));
                hv.w = f32_to_bf16_rne(v.w); lv.w = f32_to_bf16_rne(v.w - bf16_hi_f32(hv.w));
                int off = (s * 128 + q * 8) ^ ((s & 7) << 4);
                *reinterpret_cast<ushort4*>((char*)bhi + off) = hv;
                *reinterpret_cast<ushort4*>((char*)blo + off) = lv;
            }
            __syncthreads();
        }
    }

    // ---- cross-lane top-2 merge over the 16 lanes sharing each row ----
    #pragma unroll
    for (int off = 1; off <= 8; off <<= 1) {
        #pragma unroll
        for (int rt = 0; rt < 2; ++rt)
            #pragma unroll
            for (int r = 0; r < 4; ++r) {
                float w1 = __shfl_xor(v1[rt][r], off);
                int   j1 = __shfl_xor(i1[rt][r], off);
                float w2 = __shfl_xor(v2[rt][r], off);
                int   j2 = __shfl_xor(i2[rt][r], off);
                bool firstWins = (w1 < v1[rt][r]) || (w1 == v1[rt][r] && j1 < i1[rt][r]);
                if (firstWins) {
                    float nv2; int ni2;
                    if (v1[rt][r] < w2 || (v1[rt][r] == w2 && i1[rt][r] < j2)) { nv2 = v1[rt][r]; ni2 = i1[rt][r]; }
                    else                                                       { nv2 = w2;        ni2 = j2; }
                    v1[rt][r] = w1; i1[rt][r] = j1; v2[rt][r] = nv2; i2[rt][r] = ni2;
                } else {
                    if (w1 < v2[rt][r] || (w1 == v2[rt][r] && j1 < i2[rt][r])) { v2[rt][r] = w1; i2[rt][r] = j1; }
                }
            }
    }
    if ((l & 15) == 0) {
        #pragma unroll
        for (int rt = 0; rt < 2; ++rt)
            #pragma unroll
            for (int r = 0; r < 4; ++r)
                top2s[(w << 5) + (rt << 4) + ((l >> 4) << 2) + r] = make_int2(i1[rt][r], i2[rt][r]);
    }
    __syncthreads();

    // ---- f64 refine: half-wave per row, exact distances of top-2, write outputs ----
    const int half = t >> 5;
    const int hl   = t & 31;
    double acc_c = 0.0;
    for (int it = 0; it < 16; ++it) {
        int  row  = it * 8 + half;          // 0..127
        int  lg   = lt * TRB + row;
        long grow = (long)bh * Lc + lg;
        int2 zz   = top2s[row];
        const float* Ar = Avec + row * DKc;
        float vlo  = Ar[hl];
        float vhi  = Ar[hl + 32];
        const float* C1 = Bp + (size_t)zz.x * DKc;
        const float* C2 = Bp + (size_t)zz.y * DKc;
        float c1lo = C1[hl], c1hi = C1[hl + 32];
        float c2lo = C2[hl], c2hi = C2[hl + 32];
        double s_vv  = (double)vlo * vlo  + (double)vhi * vhi;
        double s_vc1 = (double)vlo * c1lo + (double)vhi * c1hi;
        double s_vc2 = (double)vlo * c2lo + (double)vhi * c2hi;
        double s_c1  = (double)c1lo * c1lo + (double)c1hi * c1hi;
        double s_c2  = (double)c2lo * c2lo + (double)c2hi * c2hi;
        #pragma unroll
        for (int off = 16; off; off >>= 1) {
            s_vv  += __shfl_xor(s_vv,  off);
            s_vc1 += __shfl_xor(s_vc1, off);
            s_vc2 += __shfl_xor(s_vc2, off);
            s_c1  += __shfl_xor(s_c1,  off);
            s_c2  += __shfl_xor(s_c2,  off);
        }
        double d1 = s_vv - 2.0 * s_vc1 + s_c1;
        double d2 = s_vv - 2.0 * s_vc2 + s_c2;
        bool second = (d2 < d1) || (d2 == d1 && zz.y < zz.x);
        int    zsel = second ? zz.y : zz.x;
        double dsel = second ? d2 : d1;
        float  cslo = second ? c2lo : c1lo;
        float  cshi = second ? c2hi : c1hi;
        double err  = dsel > 0.0 ? dsel : 0.0;
        out_vh[grow * DKc + hl]      = cslo;
        out_vh[grow * DKc + hl + 32] = cshi;
        if (hl == 0) {
            out_z[grow]   = (float)zsel;
            out_err[grow] = (float)err;
            acc_c += (double)loss_mask[b * Lc + lg] * err;
        }
    }
    if (hl == 0) wsum8[half] = acc_c;
    __syncthreads();
    if (t == 0) {
        double s = 0.0;
        #pragma unroll
        for (int i = 0; i < 8; ++i) s += wsum8[i];
        partials[blockIdx.y * gridDim.x + blockIdx.x] = s;
    }
}

// ---------------- finalize ----------------
__global__ __launch_bounds__(256) void finalize_kernel(
        const double* __restrict__ partials, int n,
        float* __restrict__ out_lcommit, float* __restrict__ out_lcode) {
    __shared__ double sh[256];
    double a = 0.0;
    for (int i = threadIdx.x; i < n; i += 256) a += partials[i];
    sh[threadIdx.x] = a;
    __syncthreads();
    for (int s = 128; s; s >>= 1) {
        if (threadIdx.x < s) sh[threadIdx.x] += sh[threadIdx.x + s];
        __syncthreads();
    }
    if (threadIdx.x == 0) {
        double lc = sh[0] / (double)(Bc * Lc);
        *out_lcommit = (float)lc;
        *out_lcode   = 0.0f;
    }
}

extern "C" void kernel_launch(void* const* d_in, const int* in_sizes, int n_in,
                              void* d_out, int out_size, void* d_ws, size_t ws_size,
                              hipStream_t stream) {
    const float* vecs      = (const float*)d_in[0];
    const float* c_sum     = (const float*)d_in[1];
    const float* c_count   = (const float*)d_in[2];
    const float* loss_mask = (const float*)d_in[3];
    (void)in_sizes; (void)n_in; (void)out_size; (void)ws_size;

    char* ws = (char*)d_ws;
    float*  c        = (float*)(ws + WS_C_OFF);
    float*  c2       = (float*)(ws + WS_C2_OFF);
    double* partials = (double*)(ws + WS_PART_OFF);

    float* out = (float*)d_out;
    float* out_vh      = out;                                   // B*H*L*DK
    float* out_z       = out + (size_t)Bc * Hc * Lc * DKc;      // B*H*L
    float* out_lcommit = out_z + (size_t)Bc * Hc * Lc;          // 1
    float* out_lcode   = out_lcommit + 1;                       // 1
    float* out_err     = out_lcode + 1;                         // B*H*L

    prep_kernel<<<(Hc * Sc * 64) / 256, 256, 0, stream>>>(c_sum, c_count, c, c2);

    dim3 g2(Lc / TRB, Bc * Hc);         // (32, 64) -> 2048 blocks
    vq_mfma_kernel<<<g2, 256, 0, stream>>>(vecs, c, c2, loss_mask,
                                           out_vh, out_z, out_err, partials);

    finalize_kernel<<<1, 256, 0, stream>>>(partials, NPART, out_lcommit, out_lcode);
}

// Round 5
// 203.691 us; speedup vs baseline: 2.1245x; 1.6478x over previous
//
#include <hip/hip_runtime.h>
#include <hip/hip_bf16.h>

// LearnableVQ forward on MI355X — MFMA (bf16 3-term split) distance GEMM, v2.
// B=8 H=8 L=4096 DK=64 S=512. Inputs f32; output f32, concatenated:
//   vecs_hat[B,H,L,DK] | z[B,H,L] | l_commit | l_codebook | errs2[B,H,L]
// v2: codebook pre-split/pre-swizzled in prep (no per-block conversion);
//     A fragments direct from global (no A LDS) -> 35 KiB LDS, 3 blocks/CU;
//     refine uses delta-trick (1 f64 butterfly) + f32 err butterfly.

#define Bc 8
#define Hc 8
#define Lc 4096
#define DKc 64
#define Sc 512

typedef __attribute__((ext_vector_type(8))) short bf16x8;
typedef __attribute__((ext_vector_type(8))) unsigned short u16x8;
typedef __attribute__((ext_vector_type(4))) float f32x4;

// ---------------- ws layout (bytes) ----------------
#define WS_C_OFF    0u          // H*S*DK f32           = 1,048,576
#define WS_C2_OFF   1048576u    // H*S f32              =    16,384
#define WS_CBH_OFF  1064960u    // H*S*DK bf16 hi (swz) =   524,288
#define WS_CBL_OFF  1589248u    // H*S*DK bf16 lo (swz) =   524,288
#define WS_PART_OFF 2113536u    // 2048 doubles         =    16,384
#define NPART       2048

__device__ __forceinline__ unsigned short f32_to_bf16_rne(float x) {
    unsigned u = __float_as_uint(x);
    unsigned r = (u + 0x7FFFu + ((u >> 16) & 1u)) >> 16;
    return (unsigned short)r;
}
__device__ __forceinline__ float bf16_hi_f32(unsigned short h) {
    return __uint_as_float(((unsigned)h) << 16);
}

// ---------------- prep: normalize codebook; produce c2 + pre-split pre-swizzled bf16 ----------------
__global__ __launch_bounds__(256) void prep_kernel(
        const float* __restrict__ c_sum,
        const float* __restrict__ c_count,
        float* __restrict__ c,
        float* __restrict__ c2,
        unsigned short* __restrict__ cbh,
        unsigned short* __restrict__ cbl) {
    int row  = (blockIdx.x * blockDim.x + threadIdx.x) >> 6;   // h*512 + s
    int lane = threadIdx.x & 63;
    float cnt = c_count[row];
    float inv = 1.0f / fmaxf(cnt, 0.01f);
    float val = c_sum[row * DKc + lane] * inv;
    c[row * DKc + lane] = val;
    unsigned short hi = f32_to_bf16_rne(val);
    unsigned short lo = f32_to_bf16_rne(val - bf16_hi_f32(hi));
    int s = row & (Sc - 1);
    size_t hbase = (size_t)(row >> 9) * (Sc * 128);            // bytes per head: 512*128
    int boff = (s * 128 + lane * 2) ^ ((s & 7) << 4);          // swizzled row layout
    *(unsigned short*)((char*)cbh + hbase + boff) = hi;
    *(unsigned short*)((char*)cbl + hbase + boff) = lo;
    float sq = val * val;
    #pragma unroll
    for (int off = 32; off; off >>= 1) sq += __shfl_xor(sq, off);
    if (lane == 0) c2[row] = sq;
}

// ---------------- fused MFMA kernel ----------------
// 256 thr (4 waves), 128 rows/block; wave owns 32 rows (2 row-tiles of 16).
// Codes chunked 128; B staged in LDS by pure copy (pre-swizzled global).
#define TRB 128

__global__ __launch_bounds__(256, 3) void vq_mfma_kernel(
        const float* __restrict__ vecs,
        const float* __restrict__ c,
        const float* __restrict__ c2,
        const unsigned short* __restrict__ cbh,
        const unsigned short* __restrict__ cbl,
        const float* __restrict__ loss_mask,
        float* __restrict__ out_vh,
        float* __restrict__ out_z,
        float* __restrict__ out_err,
        double* __restrict__ partials) {
    __shared__ unsigned short bhi[128 * DKc];   // 16 KiB (swizzled content)
    __shared__ unsigned short blo[128 * DKc];   // 16 KiB
    __shared__ float  c2_lds[Sc];               //  2 KiB
    __shared__ int2   top2s[TRB];               //  1 KiB
    __shared__ double wsum8[8];                 // total ~35.2 KiB

    const int t  = threadIdx.x;
    const int l  = t & 63;
    const int w  = t >> 6;
    const int bh = blockIdx.y;          // b*H + h
    const int h  = bh & (Hc - 1);
    const int b  = bh >> 3;
    const int lt = blockIdx.x;          // l-tile (128 rows)

    const float* Avec = vecs + ((size_t)bh * Lc + (size_t)lt * TRB) * DKc;
    const float* Bp   = c + (size_t)h * Sc * DKc;
    const char*  cbh_h = (const char*)cbh + (size_t)h * (Sc * 128);
    const char*  cbl_h = (const char*)cbl + (size_t)h * (Sc * 128);

    for (int i = t; i < Sc; i += 256) c2_lds[i] = c2[h * Sc + i];

    // ---- A fragments direct from global, convert in-reg (once per block) ----
    bf16x8 fah[2][2], fal[2][2];
    {
        const int rloc = (w << 5) + (l & 15);
        #pragma unroll
        for (int rt = 0; rt < 2; ++rt) {
            const float* Ar = Avec + (size_t)(rloc + (rt << 4)) * DKc;
            #pragma unroll
            for (int ks = 0; ks < 2; ++ks) {
                int k0 = (ks << 5) + ((l >> 4) << 3);
                float4 p0 = *reinterpret_cast<const float4*>(Ar + k0);
                float4 p1 = *reinterpret_cast<const float4*>(Ar + k0 + 4);
                float e[8] = {p0.x, p0.y, p0.z, p0.w, p1.x, p1.y, p1.z, p1.w};
                bf16x8 hv, lv;
                #pragma unroll
                for (int i = 0; i < 8; ++i) {
                    unsigned short hi = f32_to_bf16_rne(e[i]);
                    hv[i] = (short)hi;
                    lv[i] = (short)f32_to_bf16_rne(e[i] - bf16_hi_f32(hi));
                }
                fah[rt][ks] = hv;
                fal[rt][ks] = lv;
            }
        }
    }

    // per-lane top-2 state: rows (w*32 + rt*16 + (l>>4)*4 + r)
    float v1[2][4], v2[2][4];
    int   i1[2][4], i2[2][4];
    #pragma unroll
    for (int rt = 0; rt < 2; ++rt)
        #pragma unroll
        for (int r = 0; r < 4; ++r) { v1[rt][r] = 3.0e38f; v2[rt][r] = 3.0e38f; i1[rt][r] = 0; i2[rt][r] = 0; }

    // ---- stage chunk 0 (pure copy, both sides linear; swizzle is baked in) ----
    {
        const char* sh_ = cbh_h + w * 4096;
        const char* sl_ = cbl_h + w * 4096;
        char* dh = (char*)bhi + w * 4096;
        char* dl = (char*)blo + w * 4096;
        #pragma unroll
        for (int i = 0; i < 4; ++i) {
            *(u16x8*)(dh + i * 1024 + l * 16) = *(const u16x8*)(sh_ + i * 1024 + l * 16);
            *(u16x8*)(dl + i * 1024 + l * 16) = *(const u16x8*)(sl_ + i * 1024 + l * 16);
        }
    }
    __syncthreads();

    for (int chunk = 0; chunk < 4; ++chunk) {
        f32x4 acc[2][8];
        #pragma unroll
        for (int rt = 0; rt < 2; ++rt)
            #pragma unroll
            for (int j = 0; j < 8; ++j) acc[rt][j] = (f32x4){0.f, 0.f, 0.f, 0.f};

        #pragma unroll
        for (int j = 0; j < 8; ++j) {
            int crow = (j << 4) + (l & 15);
            int o0 = ((crow << 7) + ((l >> 4) << 4)) ^ ((crow & 7) << 4);
            int o1 = ((crow << 7) + 64 + ((l >> 4) << 4)) ^ ((crow & 7) << 4);
            bf16x8 h0 = *reinterpret_cast<const bf16x8*>((const char*)bhi + o0);
            bf16x8 h1 = *reinterpret_cast<const bf16x8*>((const char*)bhi + o1);
            bf16x8 g0 = *reinterpret_cast<const bf16x8*>((const char*)blo + o0);
            bf16x8 g1 = *reinterpret_cast<const bf16x8*>((const char*)blo + o1);
            #pragma unroll
            for (int rt = 0; rt < 2; ++rt) {
                acc[rt][j] = __builtin_amdgcn_mfma_f32_16x16x32_bf16(fah[rt][0], h0, acc[rt][j], 0, 0, 0);
                acc[rt][j] = __builtin_amdgcn_mfma_f32_16x16x32_bf16(fah[rt][1], h1, acc[rt][j], 0, 0, 0);
                acc[rt][j] = __builtin_amdgcn_mfma_f32_16x16x32_bf16(fal[rt][0], h0, acc[rt][j], 0, 0, 0);
                acc[rt][j] = __builtin_amdgcn_mfma_f32_16x16x32_bf16(fal[rt][1], h1, acc[rt][j], 0, 0, 0);
                acc[rt][j] = __builtin_amdgcn_mfma_f32_16x16x32_bf16(fah[rt][0], g0, acc[rt][j], 0, 0, 0);
                acc[rt][j] = __builtin_amdgcn_mfma_f32_16x16x32_bf16(fah[rt][1], g1, acc[rt][j], 0, 0, 0);
            }
        }

        // fold distances into per-lane top-2 (codes ascend per lane -> earliest-index ties)
        #pragma unroll
        for (int j = 0; j < 8; ++j) {
            int code = (chunk << 7) + (j << 4) + (l & 15);
            float cc = c2_lds[code];
            #pragma unroll
            for (int rt = 0; rt < 2; ++rt)
                #pragma unroll
                for (int r = 0; r < 4; ++r) {
                    float d = fmaf(-2.0f, acc[rt][j][r], cc);
                    if (d < v1[rt][r]) { v2[rt][r] = v1[rt][r]; i2[rt][r] = i1[rt][r]; v1[rt][r] = d; i1[rt][r] = code; }
                    else if (d < v2[rt][r]) { v2[rt][r] = d; i2[rt][r] = code; }
                }
        }

        __syncthreads();    // all waves done reading bhi/blo
        if (chunk < 3) {
            const char* sh_ = cbh_h + (chunk + 1) * 16384 + w * 4096;
            const char* sl_ = cbl_h + (chunk + 1) * 16384 + w * 4096;
            char* dh = (char*)bhi + w * 4096;
            char* dl = (char*)blo + w * 4096;
            #pragma unroll
            for (int i = 0; i < 4; ++i) {
                *(u16x8*)(dh + i * 1024 + l * 16) = *(const u16x8*)(sh_ + i * 1024 + l * 16);
                *(u16x8*)(dl + i * 1024 + l * 16) = *(const u16x8*)(sl_ + i * 1024 + l * 16);
            }
            __syncthreads();
        }
    }

    // ---- cross-lane top-2 merge over the 16 lanes (cols) sharing each row ----
    #pragma unroll
    for (int off = 1; off <= 8; off <<= 1) {
        #pragma unroll
        for (int rt = 0; rt < 2; ++rt)
            #pragma unroll
            for (int r = 0; r < 4; ++r) {
                float w1 = __shfl_xor(v1[rt][r], off);
                int   j1 = __shfl_xor(i1[rt][r], off);
                float w2 = __shfl_xor(v2[rt][r], off);
                int   j2 = __shfl_xor(i2[rt][r], off);
                bool firstWins = (w1 < v1[rt][r]) || (w1 == v1[rt][r] && j1 < i1[rt][r]);
                if (firstWins) {
                    float nv2; int ni2;
                    if (v1[rt][r] < w2 || (v1[rt][r] == w2 && i1[rt][r] < j2)) { nv2 = v1[rt][r]; ni2 = i1[rt][r]; }
                    else                                                       { nv2 = w2;        ni2 = j2; }
                    v1[rt][r] = w1; i1[rt][r] = j1; v2[rt][r] = nv2; i2[rt][r] = ni2;
                } else {
                    if (w1 < v2[rt][r] || (w1 == v2[rt][r] && j1 < i2[rt][r])) { v2[rt][r] = w1; i2[rt][r] = j1; }
                }
            }
    }
    if ((l & 15) == 0) {
        #pragma unroll
        for (int rt = 0; rt < 2; ++rt)
            #pragma unroll
            for (int r = 0; r < 4; ++r)
                top2s[(w << 5) + (rt << 4) + ((l >> 4) << 2) + r] = make_int2(i1[rt][r], i2[rt][r]);
    }
    __syncthreads();

    // ---- refine: half-wave per row; exact f64 delta for z; f32 err; write outputs ----
    const int half = t >> 5;
    const int hl   = t & 31;
    double acc_c = 0.0;
    for (int it = 0; it < 16; ++it) {
        int  row  = it * 8 + half;          // 0..127
        int  lg   = lt * TRB + row;
        long grow = (long)bh * Lc + lg;
        int2 zz   = top2s[row];
        const float* Ar = Avec + (size_t)row * DKc;
        float va = Ar[hl];
        float vb = Ar[hl + 32];
        const float* C1 = Bp + (size_t)zz.x * DKc;
        const float* C2 = Bp + (size_t)zz.y * DKc;
        float a0 = C1[hl], a1 = C1[hl + 32];
        float b0 = C2[hl], b1 = C2[hl + 32];
        // d1 - d2 = sum (c1-c2)*(c1+c2-2v), exact-enough in f64
        double dd = ((double)a0 - (double)b0) * (((double)a0 + (double)b0) - 2.0 * (double)va)
                  + ((double)a1 - (double)b1) * (((double)a1 + (double)b1) - 2.0 * (double)vb);
        #pragma unroll
        for (int off = 16; off; off >>= 1) dd += __shfl_xor(dd, off);
        bool second = (dd > 0.0) || (dd == 0.0 && zz.y < zz.x);
        int   zsel = second ? zz.y : zz.x;
        float s0   = second ? b0 : a0;
        float s1   = second ? b1 : a1;
        float e = (va - s0) * (va - s0) + (vb - s1) * (vb - s1);
        #pragma unroll
        for (int off = 16; off; off >>= 1) e += __shfl_xor(e, off);
        out_vh[grow * DKc + hl]      = s0;
        out_vh[grow * DKc + hl + 32] = s1;
        if (hl == 0) {
            out_z[grow]   = (float)zsel;
            out_err[grow] = e;
            acc_c += (double)loss_mask[b * Lc + lg] * (double)e;
        }
    }
    if (hl == 0) wsum8[half] = acc_c;
    __syncthreads();
    if (t == 0) {
        double s = 0.0;
        #pragma unroll
        for (int i = 0; i < 8; ++i) s += wsum8[i];
        partials[blockIdx.y * gridDim.x + blockIdx.x] = s;
    }
}

// ---------------- finalize ----------------
__global__ __launch_bounds__(256) void finalize_kernel(
        const double* __restrict__ partials, int n,
        float* __restrict__ out_lcommit, float* __restrict__ out_lcode) {
    __shared__ double sh[256];
    double a = 0.0;
    for (int i = threadIdx.x; i < n; i += 256) a += partials[i];
    sh[threadIdx.x] = a;
    __syncthreads();
    for (int s = 128; s; s >>= 1) {
        if (threadIdx.x < s) sh[threadIdx.x] += sh[threadIdx.x + s];
        __syncthreads();
    }
    if (threadIdx.x == 0) {
        double lc = sh[0] / (double)(Bc * Lc);
        *out_lcommit = (float)lc;
        *out_lcode   = 0.0f;
    }
}

extern "C" void kernel_launch(void* const* d_in, const int* in_sizes, int n_in,
                              void* d_out, int out_size, void* d_ws, size_t ws_size,
                              hipStream_t stream) {
    const float* vecs      = (const float*)d_in[0];
    const float* c_sum     = (const float*)d_in[1];
    const float* c_count   = (const float*)d_in[2];
    const float* loss_mask = (const float*)d_in[3];
    (void)in_sizes; (void)n_in; (void)out_size; (void)ws_size;

    char* ws = (char*)d_ws;
    float*          c        = (float*)(ws + WS_C_OFF);
    float*          c2       = (float*)(ws + WS_C2_OFF);
    unsigned short* cbh      = (unsigned short*)(ws + WS_CBH_OFF);
    unsigned short* cbl      = (unsigned short*)(ws + WS_CBL_OFF);
    double*         partials = (double*)(ws + WS_PART_OFF);

    float* out = (float*)d_out;
    float* out_vh      = out;                                   // B*H*L*DK
    float* out_z       = out + (size_t)Bc * Hc * Lc * DKc;      // B*H*L
    float* out_lcommit = out_z + (size_t)Bc * Hc * Lc;          // 1
    float* out_lcode   = out_lcommit + 1;                       // 1
    float* out_err     = out_lcode + 1;                         // B*H*L

    prep_kernel<<<(Hc * Sc * 64) / 256, 256, 0, stream>>>(c_sum, c_count, c, c2, cbh, cbl);

    dim3 g2(Lc / TRB, Bc * Hc);         // (32, 64) -> 2048 blocks
    vq_mfma_kernel<<<g2, 256, 0, stream>>>(vecs, c, c2, cbh, cbl, loss_mask,
                                           out_vh, out_z, out_err, partials);

    finalize_kernel<<<1, 256, 0, stream>>>(partials, NPART, out_lcommit, out_lcode);
}